// Round 19
// baseline (327.494 us; speedup 1.0000x reference)
//
#include <hip/hip_runtime.h>
#include <hip/hip_bf16.h>

typedef __bf16 bf16_t;
typedef __bf16 bf16x4 __attribute__((ext_vector_type(4)));
typedef __bf16 bf16x8 __attribute__((ext_vector_type(8)));
typedef float f32x4 __attribute__((ext_vector_type(4)));
typedef float f32x16 __attribute__((ext_vector_type(16)));

#define MFMA16(a, b, c) __builtin_amdgcn_mfma_f32_16x16x32_bf16((a), (b), (c), 0, 0, 0)
#define MFMA32(a, b, c) __builtin_amdgcn_mfma_f32_32x32x16_bf16((a), (b), (c), 0, 0, 0)

#if __has_builtin(__builtin_amdgcn_exp2f)
#define EXP2(x) __builtin_amdgcn_exp2f(x)
#else
#define EXP2(x) exp2f(x)
#endif

__device__ inline void g2l16(const void* g, void* l) {
    __builtin_amdgcn_global_load_lds((const __attribute__((address_space(1))) void*)g,
                                     (__attribute__((address_space(3))) void*)l, 16, 0, 0);
}

// ---------------- fp32 -> (hi, lo) bf16 pair split (for x) ----------------
__global__ __launch_bounds__(256) void cvt_split_k(const float* __restrict__ src,
                                                   bf16_t* __restrict__ hi,
                                                   bf16_t* __restrict__ lo, int n4) {
    int i = blockIdx.x * 256 + threadIdx.x;
    if (i < n4) {
        float4 v = reinterpret_cast<const float4*>(src)[i];
        bf16x4 h, l;
        float f;
        f = v.x; h[0] = (__bf16)f; l[0] = (__bf16)(f - (float)h[0]);
        f = v.y; h[1] = (__bf16)f; l[1] = (__bf16)(f - (float)h[1]);
        f = v.z; h[2] = (__bf16)f; l[2] = (__bf16)(f - (float)h[2]);
        f = v.w; h[3] = (__bf16)f; l[3] = (__bf16)(f - (float)h[3]);
        reinterpret_cast<bf16x4*>(hi)[i] = h;
        reinterpret_cast<bf16x4*>(lo)[i] = l;
    }
}

// ---------------- weight conversions ----------------
__global__ __launch_bounds__(256) void cvt_weights_k(const float* __restrict__ Wq,
                                                     const float* __restrict__ Wk,
                                                     const float* __restrict__ Wv,
                                                     const float* __restrict__ Wo,
                                                     bf16_t* __restrict__ WQKh, bf16_t* __restrict__ WQKl,
                                                     bf16_t* __restrict__ Wvh, bf16_t* __restrict__ Woh) {
    const int i = blockIdx.x * 256 + threadIdx.x;   // 262144 float4 groups
    const int which = blockIdx.y;
    if (which <= 1) {
        const float c = (which == 0) ? 0.125f * 1.4426950408889634f : 1.0f;
        const int off = which * 262144;
        float4 v = reinterpret_cast<const float4*>(which == 0 ? Wq : Wk)[i];
        bf16x4 h, l;
        float f;
        f = v.x * c; h[0] = (__bf16)f; l[0] = (__bf16)(f - (float)h[0]);
        f = v.y * c; h[1] = (__bf16)f; l[1] = (__bf16)(f - (float)h[1]);
        f = v.z * c; h[2] = (__bf16)f; l[2] = (__bf16)(f - (float)h[2]);
        f = v.w * c; h[3] = (__bf16)f; l[3] = (__bf16)(f - (float)h[3]);
        reinterpret_cast<bf16x4*>(WQKh)[i + off] = h;
        reinterpret_cast<bf16x4*>(WQKl)[i + off] = l;
    } else {
        float4 v = reinterpret_cast<const float4*>(which == 2 ? Wv : Wo)[i];
        bf16x4 o;
        o[0] = (__bf16)v.x; o[1] = (__bf16)v.y; o[2] = (__bf16)v.z; o[3] = (__bf16)v.w;
        reinterpret_cast<bf16x4*>(which == 2 ? Wvh : Woh)[i] = o;
    }
}

// XCD-aware tile swizzle; LGX = log2(gridDim.x); nwg % 8 == 0.
template <int LGX>
__device__ inline void xcd_tile(int& bm, int& bn) {
    const int id = blockIdx.y * (1 << LGX) + blockIdx.x;
    const int cpx = ((1 << LGX) * gridDim.y) >> 3;
    const int swz = (id & 7) * cpx + (id >> 3);
    bn = swz & ((1 << LGX) - 1);
    bm = swz >> LGX;
}

// ---------------- GEMM: C[m,n] = sum_k A[m,k] * B[n,k] (plain bf16) ----------------
// MODE 0: bf16 row-major; MODE 1: bf16 transposed per batch (Vt) via LDS
// transpose + coalesced stores; MODE 2: fp32 row-major.
template <int MODE>
__global__ __launch_bounds__(256) void gemm_bt(const bf16_t* __restrict__ A,
                                               const bf16_t* __restrict__ B,
                                               void* __restrict__ Cout,
                                               int M, int N, int K) {
    __shared__ __align__(16) bf16_t As[128 * 32];
    __shared__ __align__(16) bf16_t Bs[128 * 32];
    const int tid = threadIdx.x;
    const int w = tid >> 6, lane = tid & 63;
    const int l15 = lane & 15, g = lane >> 4;
    const int wr = w >> 1, wc = w & 1;
    int bm, bn;
    xcd_tile<3>(bm, bn);

    const f32x4 fz = {0.f, 0.f, 0.f, 0.f};
    f32x4 acc[4][4];
#pragma unroll
    for (int m = 0; m < 4; m++)
#pragma unroll
        for (int n = 0; n < 4; n++) acc[m][n] = fz;

    const bf16_t* Ab = A + (size_t)bm * 128 * K;
    const bf16_t* Bb = B + (size_t)bn * 128 * K;
    const int rowL = w * 16 + (lane >> 2);
    const int c8 = (lane & 3) * 8;
    char* AsD = (char*)As + w * 1024;
    char* BsD = (char*)Bs + w * 1024;

    for (int k0 = 0; k0 < K; k0 += 32) {
        g2l16(Ab + (size_t)rowL * K + k0 + c8, AsD);
        g2l16(Ab + (size_t)(rowL + 64) * K + k0 + c8, AsD + 4096);
        g2l16(Bb + (size_t)rowL * K + k0 + c8, BsD);
        g2l16(Bb + (size_t)(rowL + 64) * K + k0 + c8, BsD + 4096);
        __syncthreads();

        bf16x8 af[4], bfr[4];
        const bf16x8* Ap = reinterpret_cast<const bf16x8*>(As + (wr * 64 + l15) * 32 + g * 8);
#pragma unroll
        for (int m = 0; m < 4; m++) af[m] = Ap[m * 64];
        const bf16x8* Bp = reinterpret_cast<const bf16x8*>(Bs + (wc * 64 + l15) * 32 + g * 8);
#pragma unroll
        for (int n = 0; n < 4; n++) bfr[n] = Bp[n * 64];
#pragma unroll
        for (int m = 0; m < 4; m++)
#pragma unroll
            for (int n = 0; n < 4; n++) acc[m][n] = MFMA16(af[m], bfr[n], acc[m][n]);
        __syncthreads();
    }

    if constexpr (MODE == 1) {
        // transpose C through LDS, then coalesced Vt[b][v][s] stores
        __shared__ __align__(16) bf16_t Ct[128][130];
        const int colL = wc * 64 + l15;     // + n*16 (v within tile)
        const int rowB = wr * 64 + g * 4;   // + m*16 (s within tile)
#pragma unroll
        for (int m = 0; m < 4; m++)
#pragma unroll
            for (int n = 0; n < 4; n++) {
                bf16x4 c4;
#pragma unroll
                for (int r = 0; r < 4; r++) c4[r] = (__bf16)acc[m][n][r];
                *reinterpret_cast<bf16x4*>(&Ct[colL + n * 16][rowB + m * 16]) = c4;
            }
        __syncthreads();
        const int bb = (bm * 128) >> 11;
        const int s0 = (bm * 128) & 2047;
        const int vg = tid >> 3, scc = tid & 7;
        bf16_t* Vtb = (bf16_t*)Cout + (size_t)bb * 1024 * 2048;
#pragma unroll
        for (int u = 0; u < 4; u++)
#pragma unroll
            for (int hh = 0; hh < 2; hh++) {
                const int v = u * 32 + vg;
                const int s = hh * 64 + scc * 8;
                *reinterpret_cast<int4*>(&Vtb[(size_t)(bn * 128 + v) * 2048 + s0 + s]) =
                    *reinterpret_cast<const int4*>(&Ct[v][s]);
            }
    } else {
        const int row0 = bm * 128 + wr * 64 + g * 4;
        const int col0 = bn * 128 + wc * 64 + l15;
#pragma unroll
        for (int m = 0; m < 4; m++)
#pragma unroll
            for (int n = 0; n < 4; n++)
#pragma unroll
                for (int r = 0; r < 4; r++) {
                    int row = row0 + m * 16 + r;
                    int col = col0 + n * 16;
                    float v = acc[m][n][r];
                    if (MODE == 0) {
                        ((bf16_t*)Cout)[(size_t)row * N + col] = (__bf16)v;
                    } else {
                        ((float*)Cout)[(size_t)row * N + col] = v;
                    }
                }
    }
}

// ---------------- fused Q+K split-pair GEMM ----------------
// B = concat(Wq', Wk') rows 0..2047; bn<8 -> (Qh,Ql), bn>=8 -> (Kh,Kl).
__global__ __launch_bounds__(256) void gemm_splitQK(const bf16_t* __restrict__ Ah,
                                                    const bf16_t* __restrict__ Al,
                                                    const bf16_t* __restrict__ Bh,
                                                    const bf16_t* __restrict__ Bl,
                                                    bf16_t* __restrict__ Qh,
                                                    bf16_t* __restrict__ Ql,
                                                    bf16_t* __restrict__ Kh,
                                                    bf16_t* __restrict__ Kl,
                                                    int K) {
    __shared__ __align__(16) bf16_t Ash[128 * 32];
    __shared__ __align__(16) bf16_t Asl[128 * 32];
    __shared__ __align__(16) bf16_t Bsh[128 * 32];
    __shared__ __align__(16) bf16_t Bsl[128 * 32];
    const int tid = threadIdx.x;
    const int w = tid >> 6, lane = tid & 63;
    const int l15 = lane & 15, g = lane >> 4;
    const int wr = w >> 1, wc = w & 1;
    int bm, bn;
    xcd_tile<4>(bm, bn);    // grid 16 x 64

    const f32x4 fz = {0.f, 0.f, 0.f, 0.f};
    f32x4 acc[4][4];
#pragma unroll
    for (int m = 0; m < 4; m++)
#pragma unroll
        for (int n = 0; n < 4; n++) acc[m][n] = fz;

    const size_t aoff = (size_t)bm * 128 * K;
    const size_t boff = (size_t)bn * 128 * K;
    const int rowL = w * 16 + (lane >> 2);
    const int c8 = (lane & 3) * 8;
    const size_t g0 = (size_t)rowL * K + c8;
    const size_t g1 = (size_t)(rowL + 64) * K + c8;

    for (int k0 = 0; k0 < K; k0 += 32) {
        g2l16(Ah + aoff + g0 + k0, (char*)Ash + w * 1024);
        g2l16(Ah + aoff + g1 + k0, (char*)Ash + w * 1024 + 4096);
        g2l16(Al + aoff + g0 + k0, (char*)Asl + w * 1024);
        g2l16(Al + aoff + g1 + k0, (char*)Asl + w * 1024 + 4096);
        g2l16(Bh + boff + g0 + k0, (char*)Bsh + w * 1024);
        g2l16(Bh + boff + g1 + k0, (char*)Bsh + w * 1024 + 4096);
        g2l16(Bl + boff + g0 + k0, (char*)Bsl + w * 1024);
        g2l16(Bl + boff + g1 + k0, (char*)Bsl + w * 1024 + 4096);
        __syncthreads();

        bf16x8 ah[4], al[4], bh[4], bl[4];
        const int ao = (wr * 64 + l15) * 32 + g * 8;
        const int bo = (wc * 64 + l15) * 32 + g * 8;
#pragma unroll
        for (int m = 0; m < 4; m++) {
            ah[m] = *reinterpret_cast<const bf16x8*>(Ash + ao + m * 512);
            al[m] = *reinterpret_cast<const bf16x8*>(Asl + ao + m * 512);
        }
#pragma unroll
        for (int n = 0; n < 4; n++) {
            bh[n] = *reinterpret_cast<const bf16x8*>(Bsh + bo + n * 512);
            bl[n] = *reinterpret_cast<const bf16x8*>(Bsl + bo + n * 512);
        }
#pragma unroll
        for (int m = 0; m < 4; m++)
#pragma unroll
            for (int n = 0; n < 4; n++) {
                acc[m][n] = MFMA16(ah[m], bh[n], acc[m][n]);
                acc[m][n] = MFMA16(al[m], bh[n], acc[m][n]);
                acc[m][n] = MFMA16(ah[m], bl[n], acc[m][n]);
            }
        __syncthreads();
    }

    bf16_t* Ch = (bn < 8) ? Qh : Kh;
    bf16_t* Cl = (bn < 8) ? Ql : Kl;
    const int row0 = bm * 128 + wr * 64 + g * 4;
    const int col0 = (bn * 128 + wc * 64 + l15) & 1023;
#pragma unroll
    for (int m = 0; m < 4; m++)
#pragma unroll
        for (int n = 0; n < 4; n++)
#pragma unroll
            for (int r = 0; r < 4; r++) {
                size_t idx = (size_t)(row0 + m * 16 + r) * 1024 + col0 + n * 16;
                float v = acc[m][n][r];
                bf16_t h = (__bf16)v;
                Ch[idx] = h;
                Cl[idx] = (__bf16)(v - (float)h);
            }
}

// ---------------- causal flash attention: 32x32 MFMA, paired q-tiles, XCD-local ----------------
// Swapped S^T = mfma32(K, Q): C-layout (verified) col=q=lane&31 -> each LANE owns
// one q row across the whole wave; softmax = in-lane + ONE xor-32 shuffle (max, sum).
// QK: 2 kv-subtiles x 4 kk x 3 split = 24 MFMA32 (vs 48 MFMA16); PV: 8 (vs 16).
// A/B k-mappings self-cancel (same assumed mapping on both operands; P written via
// verified C-layout and read with the same mapping V uses). R15 pairing/staging.
// VGPR budget: majors identical to R18 (st32+oacc32+q32+staging24) — watch 128 cliff.
__global__ __launch_bounds__(256) void attn_k(const bf16_t* __restrict__ Qh,
                                              const bf16_t* __restrict__ Ql,
                                              const bf16_t* __restrict__ Kh,
                                              const bf16_t* __restrict__ Kl,
                                              const bf16_t* __restrict__ Vt,
                                              bf16_t* __restrict__ Opart,
                                              float* __restrict__ ML) {
    const int L = (int)blockIdx.x + 8 * ((int)blockIdx.y + 16 * (int)blockIdx.z);
    const int px = (L >> 3) & 7;               // pair index 0..7
    const int G = (L & 7) | ((L >> 6) << 3);   // group 0..127
    const int h = G & 15;
    const int zz = G >> 4;
    const int b = zz >> 1, hf = zz & 1;
    const int tid = threadIdx.x, w = tid >> 6, lane = tid & 63;
    const int l31 = lane & 31, g5 = lane >> 5;
    const int key = l31 & 7;                   // swizzle key for this lane's rows

    __shared__ __align__(16) bf16_t Ks[4096];      // K hi [kv=64][d=64] swizzled
    __shared__ __align__(16) bf16_t Ls[4096];      // K lo
    __shared__ __align__(16) bf16_t Vs[4096];      // V^T  [v=64][kv=64] swizzled
    __shared__ __align__(16) bf16_t Ps[4][2048];   // per-wave P^T [q=32][kv=64]

    const size_t boff = (size_t)b * 2048 * 1024;
    const size_t vbase = (size_t)b * 1024 * 2048 + (size_t)(h * 64) * 2048;

    // staging: thread -> (row sr, 16B-chunk sc); rows sr and sr+32 per array.
    const int sr = tid >> 3;       // 0..31
    const int sc = tid & 7;        // 0..7
    const int wo0 = sr * 8 + (sc ^ (sr & 7));           // int4 index, swizzled
    const int wo1 = wo0 + 256;                          // (sr+32)&7 == sr&7

    int4 sK0, sK1, sL0, sL1, sV0, sV1;
#define STAGE_LOAD(T)                                                               \
    do {                                                                            \
        const int kv0_ = (T) * 64;                                                  \
        const bf16_t* kp = Kh + boff + (size_t)(kv0_ + sr) * 1024 + h * 64 + sc * 8;\
        const bf16_t* lp = Kl + boff + (size_t)(kv0_ + sr) * 1024 + h * 64 + sc * 8;\
        const bf16_t* vp = Vt + vbase + (size_t)sr * 2048 + kv0_ + sc * 8;          \
        sK0 = *(const int4*)kp; sK1 = *(const int4*)(kp + 32 * 1024);               \
        sL0 = *(const int4*)lp; sL1 = *(const int4*)(lp + 32 * 1024);               \
        sV0 = *(const int4*)vp; sV1 = *(const int4*)(vp + 32 * 2048);               \
    } while (0)
#define STAGE_WRITE()                                                               \
    do {                                                                            \
        ((int4*)Ks)[wo0] = sK0; ((int4*)Ks)[wo1] = sK1;                             \
        ((int4*)Ls)[wo0] = sL0; ((int4*)Ls)[wo1] = sL1;                             \
        ((int4*)Vs)[wo0] = sV0; ((int4*)Vs)[wo1] = sV1;                             \
    } while (0)

    bf16_t* Op = Opart + (size_t)hf * 8 * 1024 * 1024;
    float* MLp = ML + (size_t)hf * 8192 * 16 * 2;

#pragma unroll 1
    for (int it = 0; it < 2; ++it) {
        const int qt = it ? (15 - px) : px;
        const int qrw = qt * 128 + w * 32;             // wave's first q row
        const int qrow = qrw + l31;                    // this lane's q row

        // Q fragments (hi/lo): B-operand, q=l31, d = kk*16 + g5*8 + e
        bf16x8 qhf[4], qlf[4];
#pragma unroll
        for (int kk = 0; kk < 4; kk++) {
            size_t qi = boff + (size_t)qrow * 1024 + h * 64 + kk * 16 + g5 * 8;
            qhf[kk] = *reinterpret_cast<const bf16x8*>(Qh + qi);
            qlf[kk] = *reinterpret_cast<const bf16x8*>(Ql + qi);
        }

        f32x16 oacc0, oacc1;           // O^T: col q=l31, row v=(i&3)+8*(i>>2)+4*g5 (+32)
#pragma unroll
        for (int i = 0; i < 16; i++) { oacc0[i] = 0.f; oacc1[i] = 0.f; }
        float mst = -__builtin_inff(), lst = 0.f;

        const int t0 = hf ? qt + 1 : 0;
        const int t1 = hf ? 2 * qt + 1 : qt;   // inclusive
        STAGE_LOAD(t0);
        STAGE_WRITE();                 // compiler inserts vmcnt waits before reg use
        __syncthreads();

        for (int t = t0; t <= t1; ++t) {
            const int kv0 = t * 64;
            if (t < t1) STAGE_LOAD(t + 1);   // flies under this tile's compute

            if (kv0 <= qrw + 31) {   // wave-uniform: skip fully-masked tiles
                // ---- QK^T swapped (S^T; split precision: 3 MFMA32 per kk) ----
                f32x16 st0, st1;
#pragma unroll
                for (int i = 0; i < 16; i++) { st0[i] = 0.f; st1[i] = 0.f; }
                __builtin_amdgcn_s_setprio(1);
#pragma unroll
                for (int kk = 0; kk < 4; kk++) {
                    const int cs = (((kk << 1) | g5) ^ key) << 3;
                    bf16x8 kh0 = *reinterpret_cast<const bf16x8*>(&Ks[l31 * 64 + cs]);
                    bf16x8 kl0 = *reinterpret_cast<const bf16x8*>(&Ls[l31 * 64 + cs]);
                    bf16x8 kh1 = *reinterpret_cast<const bf16x8*>(&Ks[(l31 + 32) * 64 + cs]);
                    bf16x8 kl1 = *reinterpret_cast<const bf16x8*>(&Ls[(l31 + 32) * 64 + cs]);
                    st0 = MFMA32(kh0, qhf[kk], st0);
                    st0 = MFMA32(kh0, qlf[kk], st0);
                    st0 = MFMA32(kl0, qhf[kk], st0);
                    st1 = MFMA32(kh1, qhf[kk], st1);
                    st1 = MFMA32(kh1, qlf[kk], st1);
                    st1 = MFMA32(kl1, qhf[kk], st1);
                }
                __builtin_amdgcn_s_setprio(0);

                // ---- in-lane softmax (base-2): one q row per lane ----
                if (kv0 + 63 > qrow) {          // mask needed for this lane's row
                    const int klim = qrow - kv0;
#pragma unroll
                    for (int i = 0; i < 16; i++) {
                        const int kvl = (i & 3) + 8 * (i >> 2) + 4 * g5;
                        if (kvl > klim) st0[i] = -__builtin_inff();
                        if (kvl + 32 > klim) st1[i] = -__builtin_inff();
                    }
                }
                float pmax = -__builtin_inff();
#pragma unroll
                for (int i = 0; i < 16; i++) {
                    pmax = fmaxf(pmax, st0[i]);
                    pmax = fmaxf(pmax, st1[i]);
                }
                pmax = fmaxf(pmax, __shfl_xor(pmax, 32));
                const float mn = fmaxf(mst, pmax);
                const float alpha = EXP2(mst - mn);
                mst = mn;
                float rs = 0.f;
#pragma unroll
                for (int i = 0; i < 16; i++) {
                    float p0 = EXP2(st0[i] - mn);
                    float p1 = EXP2(st1[i] - mn);
                    st0[i] = p0;
                    st1[i] = p1;
                    rs += p0 + p1;
                }
                rs += __shfl_xor(rs, 32);
                lst = lst * alpha + rs;
#pragma unroll
                for (int i = 0; i < 16; i++) { oacc0[i] *= alpha; oacc1[i] *= alpha; }

                // ---- P^T -> per-wave LDS, packed 8B: row q=l31, kv=r+8*qd+4*g5(+32) ----
#pragma unroll
                for (int qd = 0; qd < 4; qd++) {
                    bf16x4 p4a, p4b;
#pragma unroll
                    for (int r = 0; r < 4; r++) {
                        p4a[r] = (__bf16)st0[4 * qd + r];
                        p4b[r] = (__bf16)st1[4 * qd + r];
                    }
                    const int ca = (qd ^ key) << 3;
                    const int cb = ((4 + qd) ^ key) << 3;
                    *reinterpret_cast<bf16x4*>(&Ps[w][l31 * 64 + ca + 4 * g5]) = p4a;
                    *reinterpret_cast<bf16x4*>(&Ps[w][l31 * 64 + cb + 4 * g5]) = p4b;
                }

                asm volatile("s_waitcnt lgkmcnt(0)" ::: "memory");
                __builtin_amdgcn_sched_barrier(0);

                // ---- PV: O^T += V^T · P  (A = V^T, B = P) ----
                __builtin_amdgcn_s_setprio(1);
#pragma unroll
                for (int kks = 0; kks < 4; kks++) {
                    const int cs = (((kks << 1) | g5) ^ key) << 3;
                    bf16x8 pa = *reinterpret_cast<const bf16x8*>(&Ps[w][l31 * 64 + cs]);
                    bf16x8 vf0 = *reinterpret_cast<const bf16x8*>(&Vs[l31 * 64 + cs]);
                    bf16x8 vf1 = *reinterpret_cast<const bf16x8*>(&Vs[(l31 + 32) * 64 + cs]);
                    oacc0 = MFMA32(vf0, pa, oacc0);
                    oacc1 = MFMA32(vf1, pa, oacc1);
                }
                __builtin_amdgcn_s_setprio(0);
            }
            __syncthreads();                 // all waves done reading Ks/Ls/Vs
            if (t < t1) STAGE_WRITE();       // loads arrived long ago; write swizzled
            __syncthreads();                 // writes visible for next tile
        }

        // ---- epilogue: unnormalized partial (packed 8B) + (m,l) by lanes 0..31 ----
#pragma unroll
        for (int qd = 0; qd < 4; qd++) {
            bf16x4 o4a, o4b;
#pragma unroll
            for (int r = 0; r < 4; r++) {
                o4a[r] = (__bf16)oacc0[4 * qd + r];
                o4b[r] = (__bf16)oacc1[4 * qd + r];
            }
            const size_t base = boff + (size_t)qrow * 1024 + h * 64 + 8 * qd + 4 * g5;
            *reinterpret_cast<bf16x4*>(&Op[base]) = o4a;
            *reinterpret_cast<bf16x4*>(&Op[base + 32]) = o4b;
        }
        if (g5 == 0) {
            const int grow = b * 2048 + qrow;
            MLp[(grow * 16 + h) * 2 + 0] = mst;
            MLp[(grow * 16 + h) * 2 + 1] = lst;
        }
        // loop's final __syncthreads already passed; LDS safe to restage next item
    }
#undef STAGE_LOAD
#undef STAGE_WRITE
}

// ---------------- split-KV combine: O = (w1*O1 + w2*O2) ----------------
__global__ __launch_bounds__(256) void attn_combine_k(const bf16_t* __restrict__ Op0,
                                                      const bf16_t* __restrict__ Op1,
                                                      const float* __restrict__ ML,
                                                      bf16_t* __restrict__ O) {
    const int t = blockIdx.x * 256 + threadIdx.x;   // 8-elem groups, 1,048,576 total
    const int row = t >> 7;
    const int h = (t >> 3) & 15;
    const float m1 = ML[(row * 16 + h) * 2 + 0];
    const float l1 = ML[(row * 16 + h) * 2 + 1];
    const float m2 = ML[(8192 * 16 + row * 16 + h) * 2 + 0];
    const float l2 = ML[(8192 * 16 + row * 16 + h) * 2 + 1];
    const float mx = fmaxf(m1, m2);
    float w1 = (l1 > 0.f) ? EXP2(m1 - mx) : 0.f;
    float w2 = (l2 > 0.f) ? EXP2(m2 - mx) : 0.f;
    const float inv = 1.f / (l1 * w1 + l2 * w2);
    w1 *= inv; w2 *= inv;
    bf16x8 a = reinterpret_cast<const bf16x8*>(Op0)[t];
    bf16x8 c = reinterpret_cast<const bf16x8*>(Op1)[t];
    bf16x8 o;
#pragma unroll
    for (int i = 0; i < 8; i++) o[i] = (__bf16)((float)a[i] * w1 + (float)c[i] * w2);
    reinterpret_cast<bf16x8*>(O)[t] = o;
}

extern "C" void kernel_launch(void* const* d_in, const int* in_sizes, int n_in,
                              void* d_out, int out_size, void* d_ws, size_t ws_size,
                              hipStream_t stream) {
    const float* x  = (const float*)d_in[0];
    const float* Wq = (const float*)d_in[1];
    const float* Wk = (const float*)d_in[2];
    const float* Wv = (const float*)d_in[3];
    const float* Wo = (const float*)d_in[4];

    char* ws = (char*)d_ws;
    const size_t MB = (size_t)1 << 20;
    bf16_t* xh   = (bf16_t*)(ws);            // dead after projections -> Opart
    bf16_t* xl   = (bf16_t*)(ws + 16 * MB);
    bf16_t* Qh   = (bf16_t*)(ws + 32 * MB);
    bf16_t* Ql   = (bf16_t*)(ws + 48 * MB);
    bf16_t* Kh   = (bf16_t*)(ws + 64 * MB);
    bf16_t* Kl   = (bf16_t*)(ws + 80 * MB);
    bf16_t* Vt   = (bf16_t*)(ws + 96 * MB);
    bf16_t* Ob   = (bf16_t*)(ws + 112 * MB);
    bf16_t* WQKh = (bf16_t*)(ws + 128 * MB); // [2048][1024] = 4 MB; dead after proj -> ML
    bf16_t* WQKl = (bf16_t*)(ws + 132 * MB);
    bf16_t* Wvh  = (bf16_t*)(ws + 136 * MB);
    bf16_t* Woh  = (bf16_t*)(ws + 138 * MB);
    bf16_t* Opart = (bf16_t*)(ws);           // [2][8192][1024] bf16 = 32 MB
    float*  ML    = (float*)(ws + 128 * MB); // [2][8192][16][2] f32 = 2 MB

    // conversions / splits.  x: 2,097,152 float4; each W: 262,144 float4.
    cvt_split_k<<<8192, 256, 0, stream>>>(x, xh, xl, 2097152);
    cvt_weights_k<<<dim3(1024, 4), 256, 0, stream>>>(Wq, Wk, Wv, Wo,
                                                     WQKh, WQKl, Wvh, Woh);

    // projections: fused Q+K (N=2048), then V
    gemm_splitQK<<<dim3(16, 64), 256, 0, stream>>>(xh, xl, WQKh, WQKl,
                                                   Qh, Ql, Kh, Kl, 1024);
    gemm_bt<1><<<dim3(8, 64), 256, 0, stream>>>(xh, Wvh, Vt, 8192, 1024, 1024);

    // attention: paired q-tiles, XCD-local (h,b,hf) groups, 1024 identical blocks
    attn_k<<<dim3(8, 16, 8), 256, 0, stream>>>(Qh, Ql, Kh, Kl, Vt, Opart, ML);
    attn_combine_k<<<4096, 256, 0, stream>>>(Opart, Opart + (size_t)8 * 1024 * 1024, ML, Ob);

    // output projection (fp32 epilogue to d_out)
    gemm_bt<2><<<dim3(8, 64), 256, 0, stream>>>(Ob, Woh, d_out, 8192, 1024, 1024);
}

// Round 20
// 288.642 us; speedup vs baseline: 1.1346x; 1.1346x over previous
//
#include <hip/hip_runtime.h>
#include <hip/hip_bf16.h>

typedef __bf16 bf16_t;
typedef __bf16 bf16x4 __attribute__((ext_vector_type(4)));
typedef __bf16 bf16x8 __attribute__((ext_vector_type(8)));
typedef float f32x4 __attribute__((ext_vector_type(4)));

#define MFMA16(a, b, c) __builtin_amdgcn_mfma_f32_16x16x32_bf16((a), (b), (c), 0, 0, 0)

#if __has_builtin(__builtin_amdgcn_exp2f)
#define EXP2(x) __builtin_amdgcn_exp2f(x)
#else
#define EXP2(x) exp2f(x)
#endif

__device__ inline void g2l16(const void* g, void* l) {
    __builtin_amdgcn_global_load_lds((const __attribute__((address_space(1))) void*)g,
                                     (__attribute__((address_space(3))) void*)l, 16, 0, 0);
}

// ---------------- fp32 -> (hi, lo) bf16 pair split (for x) ----------------
__global__ __launch_bounds__(256) void cvt_split_k(const float* __restrict__ src,
                                                   bf16_t* __restrict__ hi,
                                                   bf16_t* __restrict__ lo, int n4) {
    int i = blockIdx.x * 256 + threadIdx.x;
    if (i < n4) {
        float4 v = reinterpret_cast<const float4*>(src)[i];
        bf16x4 h, l;
        float f;
        f = v.x; h[0] = (__bf16)f; l[0] = (__bf16)(f - (float)h[0]);
        f = v.y; h[1] = (__bf16)f; l[1] = (__bf16)(f - (float)h[1]);
        f = v.z; h[2] = (__bf16)f; l[2] = (__bf16)(f - (float)h[2]);
        f = v.w; h[3] = (__bf16)f; l[3] = (__bf16)(f - (float)h[3]);
        reinterpret_cast<bf16x4*>(hi)[i] = h;
        reinterpret_cast<bf16x4*>(lo)[i] = l;
    }
}

// ---------------- weight conversions ----------------
// which 0: Wq * 0.125*log2e split -> rows [0,1024) of (WQKh, WQKl)
// which 1: Wk split -> rows [1024,2048) of (WQKh, WQKl)
// which 2: Wv -> Wvh;  which 3: Wo -> Woh
__global__ __launch_bounds__(256) void cvt_weights_k(const float* __restrict__ Wq,
                                                     const float* __restrict__ Wk,
                                                     const float* __restrict__ Wv,
                                                     const float* __restrict__ Wo,
                                                     bf16_t* __restrict__ WQKh, bf16_t* __restrict__ WQKl,
                                                     bf16_t* __restrict__ Wvh, bf16_t* __restrict__ Woh) {
    const int i = blockIdx.x * 256 + threadIdx.x;   // 262144 float4 groups
    const int which = blockIdx.y;
    if (which <= 1) {
        const float c = (which == 0) ? 0.125f * 1.4426950408889634f : 1.0f;
        const int off = which * 262144;
        float4 v = reinterpret_cast<const float4*>(which == 0 ? Wq : Wk)[i];
        bf16x4 h, l;
        float f;
        f = v.x * c; h[0] = (__bf16)f; l[0] = (__bf16)(f - (float)h[0]);
        f = v.y * c; h[1] = (__bf16)f; l[1] = (__bf16)(f - (float)h[1]);
        f = v.z * c; h[2] = (__bf16)f; l[2] = (__bf16)(f - (float)h[2]);
        f = v.w * c; h[3] = (__bf16)f; l[3] = (__bf16)(f - (float)h[3]);
        reinterpret_cast<bf16x4*>(WQKh)[i + off] = h;
        reinterpret_cast<bf16x4*>(WQKl)[i + off] = l;
    } else {
        float4 v = reinterpret_cast<const float4*>(which == 2 ? Wv : Wo)[i];
        bf16x4 o;
        o[0] = (__bf16)v.x; o[1] = (__bf16)v.y; o[2] = (__bf16)v.z; o[3] = (__bf16)v.w;
        reinterpret_cast<bf16x4*>(which == 2 ? Wvh : Woh)[i] = o;
    }
}

// XCD-aware tile swizzle; LGX = log2(gridDim.x); nwg % 8 == 0.
template <int LGX>
__device__ inline void xcd_tile(int& bm, int& bn) {
    const int id = blockIdx.y * (1 << LGX) + blockIdx.x;
    const int cpx = ((1 << LGX) * gridDim.y) >> 3;
    const int swz = (id & 7) * cpx + (id >> 3);
    bn = swz & ((1 << LGX) - 1);
    bm = swz >> LGX;
}

// ---------------- GEMM: C[m,n] = sum_k A[m,k] * B[n,k] (plain bf16) ----------------
// MODE 0: bf16 row-major; MODE 1: bf16 transposed per batch (Vt) via LDS
// transpose + coalesced stores; MODE 2: fp32 row-major.
template <int MODE>
__global__ __launch_bounds__(256) void gemm_bt(const bf16_t* __restrict__ A,
                                               const bf16_t* __restrict__ B,
                                               void* __restrict__ Cout,
                                               int M, int N, int K) {
    __shared__ __align__(16) bf16_t As[128 * 32];
    __shared__ __align__(16) bf16_t Bs[128 * 32];
    const int tid = threadIdx.x;
    const int w = tid >> 6, lane = tid & 63;
    const int l15 = lane & 15, g = lane >> 4;
    const int wr = w >> 1, wc = w & 1;
    int bm, bn;
    xcd_tile<3>(bm, bn);

    const f32x4 fz = {0.f, 0.f, 0.f, 0.f};
    f32x4 acc[4][4];
#pragma unroll
    for (int m = 0; m < 4; m++)
#pragma unroll
        for (int n = 0; n < 4; n++) acc[m][n] = fz;

    const bf16_t* Ab = A + (size_t)bm * 128 * K;
    const bf16_t* Bb = B + (size_t)bn * 128 * K;
    const int rowL = w * 16 + (lane >> 2);
    const int c8 = (lane & 3) * 8;
    char* AsD = (char*)As + w * 1024;
    char* BsD = (char*)Bs + w * 1024;

    for (int k0 = 0; k0 < K; k0 += 32) {
        g2l16(Ab + (size_t)rowL * K + k0 + c8, AsD);
        g2l16(Ab + (size_t)(rowL + 64) * K + k0 + c8, AsD + 4096);
        g2l16(Bb + (size_t)rowL * K + k0 + c8, BsD);
        g2l16(Bb + (size_t)(rowL + 64) * K + k0 + c8, BsD + 4096);
        __syncthreads();

        bf16x8 af[4], bfr[4];
        const bf16x8* Ap = reinterpret_cast<const bf16x8*>(As + (wr * 64 + l15) * 32 + g * 8);
#pragma unroll
        for (int m = 0; m < 4; m++) af[m] = Ap[m * 64];
        const bf16x8* Bp = reinterpret_cast<const bf16x8*>(Bs + (wc * 64 + l15) * 32 + g * 8);
#pragma unroll
        for (int n = 0; n < 4; n++) bfr[n] = Bp[n * 64];
#pragma unroll
        for (int m = 0; m < 4; m++)
#pragma unroll
            for (int n = 0; n < 4; n++) acc[m][n] = MFMA16(af[m], bfr[n], acc[m][n]);
        __syncthreads();
    }

    if constexpr (MODE == 1) {
        // transpose C through LDS, then coalesced Vt[b][v][s] stores
        __shared__ __align__(16) bf16_t Ct[128][130];
        const int colL = wc * 64 + l15;     // + n*16 (v within tile)
        const int rowB = wr * 64 + g * 4;   // + m*16 (s within tile)
#pragma unroll
        for (int m = 0; m < 4; m++)
#pragma unroll
            for (int n = 0; n < 4; n++) {
                bf16x4 c4;
#pragma unroll
                for (int r = 0; r < 4; r++) c4[r] = (__bf16)acc[m][n][r];
                *reinterpret_cast<bf16x4*>(&Ct[colL + n * 16][rowB + m * 16]) = c4;
            }
        __syncthreads();
        const int bb = (bm * 128) >> 11;
        const int s0 = (bm * 128) & 2047;
        const int vg = tid >> 3, scc = tid & 7;
        bf16_t* Vtb = (bf16_t*)Cout + (size_t)bb * 1024 * 2048;
#pragma unroll
        for (int u = 0; u < 4; u++)
#pragma unroll
            for (int hh = 0; hh < 2; hh++) {
                const int v = u * 32 + vg;
                const int s = hh * 64 + scc * 8;
                *reinterpret_cast<int4*>(&Vtb[(size_t)(bn * 128 + v) * 2048 + s0 + s]) =
                    *reinterpret_cast<const int4*>(&Ct[v][s]);
            }
    } else {
        const int row0 = bm * 128 + wr * 64 + g * 4;
        const int col0 = bn * 128 + wc * 64 + l15;
#pragma unroll
        for (int m = 0; m < 4; m++)
#pragma unroll
            for (int n = 0; n < 4; n++)
#pragma unroll
                for (int r = 0; r < 4; r++) {
                    int row = row0 + m * 16 + r;
                    int col = col0 + n * 16;
                    float v = acc[m][n][r];
                    if (MODE == 0) {
                        ((bf16_t*)Cout)[(size_t)row * N + col] = (__bf16)v;
                    } else {
                        ((float*)Cout)[(size_t)row * N + col] = v;
                    }
                }
    }
}

// ---------------- fused Q+K split-pair GEMM ----------------
// B = concat(Wq', Wk') rows 0..2047; bn<8 -> (Qh,Ql), bn>=8 -> (Kh,Kl).
__global__ __launch_bounds__(256) void gemm_splitQK(const bf16_t* __restrict__ Ah,
                                                    const bf16_t* __restrict__ Al,
                                                    const bf16_t* __restrict__ Bh,
                                                    const bf16_t* __restrict__ Bl,
                                                    bf16_t* __restrict__ Qh,
                                                    bf16_t* __restrict__ Ql,
                                                    bf16_t* __restrict__ Kh,
                                                    bf16_t* __restrict__ Kl,
                                                    int K) {
    __shared__ __align__(16) bf16_t Ash[128 * 32];
    __shared__ __align__(16) bf16_t Asl[128 * 32];
    __shared__ __align__(16) bf16_t Bsh[128 * 32];
    __shared__ __align__(16) bf16_t Bsl[128 * 32];
    const int tid = threadIdx.x;
    const int w = tid >> 6, lane = tid & 63;
    const int l15 = lane & 15, g = lane >> 4;
    const int wr = w >> 1, wc = w & 1;
    int bm, bn;
    xcd_tile<4>(bm, bn);    // grid 16 x 64

    const f32x4 fz = {0.f, 0.f, 0.f, 0.f};
    f32x4 acc[4][4];
#pragma unroll
    for (int m = 0; m < 4; m++)
#pragma unroll
        for (int n = 0; n < 4; n++) acc[m][n] = fz;

    const size_t aoff = (size_t)bm * 128 * K;
    const size_t boff = (size_t)bn * 128 * K;
    const int rowL = w * 16 + (lane >> 2);
    const int c8 = (lane & 3) * 8;
    const size_t g0 = (size_t)rowL * K + c8;
    const size_t g1 = (size_t)(rowL + 64) * K + c8;

    for (int k0 = 0; k0 < K; k0 += 32) {
        g2l16(Ah + aoff + g0 + k0, (char*)Ash + w * 1024);
        g2l16(Ah + aoff + g1 + k0, (char*)Ash + w * 1024 + 4096);
        g2l16(Al + aoff + g0 + k0, (char*)Asl + w * 1024);
        g2l16(Al + aoff + g1 + k0, (char*)Asl + w * 1024 + 4096);
        g2l16(Bh + boff + g0 + k0, (char*)Bsh + w * 1024);
        g2l16(Bh + boff + g1 + k0, (char*)Bsh + w * 1024 + 4096);
        g2l16(Bl + boff + g0 + k0, (char*)Bsl + w * 1024);
        g2l16(Bl + boff + g1 + k0, (char*)Bsl + w * 1024 + 4096);
        __syncthreads();

        bf16x8 ah[4], al[4], bh[4], bl[4];
        const int ao = (wr * 64 + l15) * 32 + g * 8;
        const int bo = (wc * 64 + l15) * 32 + g * 8;
#pragma unroll
        for (int m = 0; m < 4; m++) {
            ah[m] = *reinterpret_cast<const bf16x8*>(Ash + ao + m * 512);
            al[m] = *reinterpret_cast<const bf16x8*>(Asl + ao + m * 512);
        }
#pragma unroll
        for (int n = 0; n < 4; n++) {
            bh[n] = *reinterpret_cast<const bf16x8*>(Bsh + bo + n * 512);
            bl[n] = *reinterpret_cast<const bf16x8*>(Bsl + bo + n * 512);
        }
#pragma unroll
        for (int m = 0; m < 4; m++)
#pragma unroll
            for (int n = 0; n < 4; n++) {
                acc[m][n] = MFMA16(ah[m], bh[n], acc[m][n]);
                acc[m][n] = MFMA16(al[m], bh[n], acc[m][n]);
                acc[m][n] = MFMA16(ah[m], bl[n], acc[m][n]);
            }
        __syncthreads();
    }

    bf16_t* Ch = (bn < 8) ? Qh : Kh;
    bf16_t* Cl = (bn < 8) ? Ql : Kl;
    const int row0 = bm * 128 + wr * 64 + g * 4;
    const int col0 = (bn * 128 + wc * 64 + l15) & 1023;
#pragma unroll
    for (int m = 0; m < 4; m++)
#pragma unroll
        for (int n = 0; n < 4; n++)
#pragma unroll
            for (int r = 0; r < 4; r++) {
                size_t idx = (size_t)(row0 + m * 16 + r) * 1024 + col0 + n * 16;
                float v = acc[m][n][r];
                bf16_t h = (__bf16)v;
                Ch[idx] = h;
                Cl[idx] = (__bf16)(v - (float)h);
            }
}

// ---------------- causal flash attention: PAIRED q-tiles + XCD-local groups ----------------
// R18 configuration (129 us): 16x16 MFMA, VGPR 120 = 4 waves/SIMD. Do NOT add
// live state (128-VGPR cliff, R16/R19 lessons) and do NOT widen MFMA (R19:
// 32x32 shape -> VGPR 132 + 4.5x bank conflicts). Block-id decode places all
// 8 px-blocks of one (h,b,hf) group on one XCD (K/V panel in that L2).
__global__ __launch_bounds__(256) void attn_k(const bf16_t* __restrict__ Qh,
                                              const bf16_t* __restrict__ Ql,
                                              const bf16_t* __restrict__ Kh,
                                              const bf16_t* __restrict__ Kl,
                                              const bf16_t* __restrict__ Vt,
                                              bf16_t* __restrict__ Opart,
                                              float* __restrict__ ML) {
    const int L = (int)blockIdx.x + 8 * ((int)blockIdx.y + 16 * (int)blockIdx.z);
    const int px = (L >> 3) & 7;               // pair index 0..7
    const int G = (L & 7) | ((L >> 6) << 3);   // group 0..127
    const int h = G & 15;
    const int zz = G >> 4;
    const int b = zz >> 1, hf = zz & 1;
    const int tid = threadIdx.x, w = tid >> 6, lane = tid & 63;
    const int l15 = lane & 15, g = lane >> 4;

    __shared__ __align__(16) bf16_t Ks[4096];      // K hi [kv=64][d=64] swizzled
    __shared__ __align__(16) bf16_t Ls[4096];      // K lo
    __shared__ __align__(16) bf16_t Vs[4096];      // V^T  [v=64][kv=64] swizzled
    __shared__ __align__(16) bf16_t Ps[4][1024];   // per-wave P [q=16][kv=64]

    const size_t boff = (size_t)b * 2048 * 1024;
    const size_t vbase = (size_t)b * 1024 * 2048 + (size_t)(h * 64) * 2048;

    // staging: thread -> (row sr, 16B-chunk sc); rows sr and sr+32 per array.
    const int sr = tid >> 3;       // 0..31
    const int sc = tid & 7;        // 0..7
    const int wo0 = sr * 8 + (sc ^ (sr & 7));           // int4 index, swizzled
    const int wo1 = wo0 + 256;                          // (sr+32)&7 == sr&7

    int4 sK0, sK1, sL0, sL1, sV0, sV1;
#define STAGE_LOAD(T)                                                               \
    do {                                                                            \
        const int kv0_ = (T) * 64;                                                  \
        const bf16_t* kp = Kh + boff + (size_t)(kv0_ + sr) * 1024 + h * 64 + sc * 8;\
        const bf16_t* lp = Kl + boff + (size_t)(kv0_ + sr) * 1024 + h * 64 + sc * 8;\
        const bf16_t* vp = Vt + vbase + (size_t)sr * 2048 + kv0_ + sc * 8;          \
        sK0 = *(const int4*)kp; sK1 = *(const int4*)(kp + 32 * 1024);               \
        sL0 = *(const int4*)lp; sL1 = *(const int4*)(lp + 32 * 1024);               \
        sV0 = *(const int4*)vp; sV1 = *(const int4*)(vp + 32 * 2048);               \
    } while (0)
#define STAGE_WRITE()                                                               \
    do {                                                                            \
        ((int4*)Ks)[wo0] = sK0; ((int4*)Ks)[wo1] = sK1;                             \
        ((int4*)Ls)[wo0] = sL0; ((int4*)Ls)[wo1] = sL1;                             \
        ((int4*)Vs)[wo0] = sV0; ((int4*)Vs)[wo1] = sV1;                             \
    } while (0)

    const f32x4 fz = {0.f, 0.f, 0.f, 0.f};
    bf16_t* Op = Opart + (size_t)hf * 8 * 1024 * 1024;
    float* MLp = ML + (size_t)hf * 8192 * 16 * 2;

#pragma unroll 1
    for (int it = 0; it < 2; ++it) {
        const int qt = it ? (15 - px) : px;
        const int qrw = qt * 128 + w * 32;             // wave's first q row

        // Q fragments (hi/lo) — B-operand layout: lane (j=l15, g) = Q[row][g*8..+8]
        bf16x8 qhf[2][2], qlf[2][2];
#pragma unroll
        for (int m = 0; m < 2; m++)
#pragma unroll
            for (int kk = 0; kk < 2; kk++) {
                size_t qi = boff + (size_t)(qrw + m * 16 + l15) * 1024 + h * 64 + kk * 32 + g * 8;
                qhf[m][kk] = *reinterpret_cast<const bf16x8*>(Qh + qi);
                qlf[m][kk] = *reinterpret_cast<const bf16x8*>(Ql + qi);
            }

        f32x4 oacc[2][4];              // O^T frag: v = n*16+g*4+r, q = l15
#pragma unroll
        for (int m = 0; m < 2; m++)
#pragma unroll
            for (int n = 0; n < 4; n++) oacc[m][n] = fz;
        float mst[2] = {-__builtin_inff(), -__builtin_inff()};
        float lst[2] = {0.f, 0.f};

        const int t0 = hf ? qt + 1 : 0;
        const int t1 = hf ? 2 * qt + 1 : qt;   // inclusive
        STAGE_LOAD(t0);
        STAGE_WRITE();                 // compiler inserts vmcnt waits before reg use
        __syncthreads();

        for (int t = t0; t <= t1; ++t) {
            const int kv0 = t * 64;
            if (t < t1) STAGE_LOAD(t + 1);   // flies under this tile's compute

            if (kv0 <= qrw + 31) {   // wave-uniform: skip fully-masked tiles
                // ---- QK^T swapped (S^T; split precision: 3 MFMAs) ----
                f32x4 st[2][4];
#pragma unroll
                for (int m = 0; m < 2; m++)
#pragma unroll
                    for (int n = 0; n < 4; n++) st[m][n] = fz;
                __builtin_amdgcn_s_setprio(1);
#pragma unroll
                for (int kk = 0; kk < 2; kk++)
#pragma unroll
                    for (int n = 0; n < 4; n++) {
                        const int off = (n * 16 + l15) * 64 + (((kk * 4 + g) ^ (l15 & 7)) << 3);
                        bf16x8 khf = *reinterpret_cast<const bf16x8*>(&Ks[off]);
                        bf16x8 klf = *reinterpret_cast<const bf16x8*>(&Ls[off]);
#pragma unroll
                        for (int m = 0; m < 2; m++) {
                            st[m][n] = MFMA16(khf, qhf[m][kk], st[m][n]);   // Kh·Qh
                            st[m][n] = MFMA16(khf, qlf[m][kk], st[m][n]);   // Kh·Ql
                            st[m][n] = MFMA16(klf, qhf[m][kk], st[m][n]);   // Kl·Qh
                        }
                    }
                __builtin_amdgcn_s_setprio(0);

                // ---- per-m: in-lane softmax (base-2) -> packed P -> PV ----
                const bool diag = (kv0 + 63 > qrw);
#pragma unroll
                for (int m = 0; m < 2; m++) {
                    const int qrow = qrw + m * 16 + l15;   // this lane's q row
                    float pmax = -__builtin_inff();
                    if (diag) {
                        const int klim = qrow - kv0;       // mask if n*16+g*4+r > klim
#pragma unroll
                        for (int n = 0; n < 4; n++)
#pragma unroll
                            for (int r = 0; r < 4; r++) {
                                float s = st[m][n][r];
                                if (n * 16 + g * 4 + r > klim) s = -__builtin_inff();
                                st[m][n][r] = s;
                                pmax = fmaxf(pmax, s);
                            }
                    } else {
#pragma unroll
                        for (int n = 0; n < 4; n++)
#pragma unroll
                            for (int r = 0; r < 4; r++) pmax = fmaxf(pmax, st[m][n][r]);
                    }
                    pmax = fmaxf(pmax, __shfl_xor(pmax, 16));
                    pmax = fmaxf(pmax, __shfl_xor(pmax, 32));
                    const float mn = fmaxf(mst[m], pmax);
                    const float alpha = EXP2(mst[m] - mn);
                    mst[m] = mn;
                    float rs = 0.f;
#pragma unroll
                    for (int n = 0; n < 4; n++)
#pragma unroll
                        for (int r = 0; r < 4; r++) {
                            float pe = EXP2(st[m][n][r] - mn);
                            st[m][n][r] = pe;
                            rs += pe;
                        }
                    rs += __shfl_xor(rs, 16);
                    rs += __shfl_xor(rs, 32);
                    lst[m] = lst[m] * alpha + rs;
#pragma unroll
                    for (int n = 0; n < 4; n++) oacc[m][n] *= alpha;

                    // P -> per-wave LDS, packed 8B: row=l15 (q), col=n*16+g*4
#pragma unroll
                    for (int n = 0; n < 4; n++) {
                        bf16x4 p4;
#pragma unroll
                        for (int r = 0; r < 4; r++) p4[r] = (__bf16)st[m][n][r];
                        const int chunk = (2 * n + (g >> 1)) ^ (l15 & 7);
                        *reinterpret_cast<bf16x4*>(&Ps[w][l15 * 64 + chunk * 8 + (g & 1) * 4]) = p4;
                    }

                    asm volatile("s_waitcnt lgkmcnt(0)" ::: "memory");
                    __builtin_amdgcn_sched_barrier(0);

                    // PV: O^T += V^T · P  (A = V^T frag, B = P frag)
                    __builtin_amdgcn_s_setprio(1);
#pragma unroll
                    for (int kk = 0; kk < 2; kk++) {
                        bf16x8 pa = *reinterpret_cast<const bf16x8*>(
                            &Ps[w][l15 * 64 + (((kk * 4 + g) ^ (l15 & 7)) << 3)]);
#pragma unroll
                        for (int n = 0; n < 4; n++) {
                            const int voff = (n * 16 + l15) * 64 + (((kk * 4 + g) ^ (l15 & 7)) << 3);
                            bf16x8 vf = *reinterpret_cast<const bf16x8*>(&Vs[voff]);
                            oacc[m][n] = MFMA16(vf, pa, oacc[m][n]);
                        }
                    }
                    __builtin_amdgcn_s_setprio(0);
                }
            }
            __syncthreads();                 // all waves done reading Ks/Ls/Vs
            if (t < t1) STAGE_WRITE();       // loads arrived long ago; write swizzled
            __syncthreads();                 // writes visible for next tile
        }

        // ---- epilogue: unnormalized partial (packed 8B) + (m,l) by g==0 lanes ----
#pragma unroll
        for (int m = 0; m < 2; m++) {
            const int qrow = qrw + m * 16 + l15;
#pragma unroll
            for (int n = 0; n < 4; n++) {
                bf16x4 o4;
#pragma unroll
                for (int r = 0; r < 4; r++) o4[r] = (__bf16)oacc[m][n][r];
                *reinterpret_cast<bf16x4*>(&Op[boff + (size_t)qrow * 1024 + h * 64 + n * 16 + g * 4]) = o4;
            }
            if (g == 0) {
                const int grow = b * 2048 + qrow;
                MLp[(grow * 16 + h) * 2 + 0] = mst[m];
                MLp[(grow * 16 + h) * 2 + 1] = lst[m];
            }
        }
        // loop's final __syncthreads already passed; LDS safe to restage next item
    }
#undef STAGE_LOAD
#undef STAGE_WRITE
}

// ---------------- split-KV combine: O = (w1*O1 + w2*O2) ----------------
__global__ __launch_bounds__(256) void attn_combine_k(const bf16_t* __restrict__ Op0,
                                                      const bf16_t* __restrict__ Op1,
                                                      const float* __restrict__ ML,
                                                      bf16_t* __restrict__ O) {
    const int t = blockIdx.x * 256 + threadIdx.x;   // 8-elem groups, 1,048,576 total
    const int row = t >> 7;
    const int h = (t >> 3) & 15;
    const float m1 = ML[(row * 16 + h) * 2 + 0];
    const float l1 = ML[(row * 16 + h) * 2 + 1];
    const float m2 = ML[(8192 * 16 + row * 16 + h) * 2 + 0];
    const float l2 = ML[(8192 * 16 + row * 16 + h) * 2 + 1];
    const float mx = fmaxf(m1, m2);
    float w1 = (l1 > 0.f) ? EXP2(m1 - mx) : 0.f;
    float w2 = (l2 > 0.f) ? EXP2(m2 - mx) : 0.f;
    const float inv = 1.f / (l1 * w1 + l2 * w2);
    w1 *= inv; w2 *= inv;
    bf16x8 a = reinterpret_cast<const bf16x8*>(Op0)[t];
    bf16x8 c = reinterpret_cast<const bf16x8*>(Op1)[t];
    bf16x8 o;
#pragma unroll
    for (int i = 0; i < 8; i++) o[i] = (__bf16)((float)a[i] * w1 + (float)c[i] * w2);
    reinterpret_cast<bf16x8*>(O)[t] = o;
}

extern "C" void kernel_launch(void* const* d_in, const int* in_sizes, int n_in,
                              void* d_out, int out_size, void* d_ws, size_t ws_size,
                              hipStream_t stream) {
    const float* x  = (const float*)d_in[0];
    const float* Wq = (const float*)d_in[1];
    const float* Wk = (const float*)d_in[2];
    const float* Wv = (const float*)d_in[3];
    const float* Wo = (const float*)d_in[4];

    char* ws = (char*)d_ws;
    const size_t MB = (size_t)1 << 20;
    bf16_t* xh   = (bf16_t*)(ws);            // dead after projections -> Opart
    bf16_t* xl   = (bf16_t*)(ws + 16 * MB);
    bf16_t* Qh   = (bf16_t*)(ws + 32 * MB);
    bf16_t* Ql   = (bf16_t*)(ws + 48 * MB);
    bf16_t* Kh   = (bf16_t*)(ws + 64 * MB);
    bf16_t* Kl   = (bf16_t*)(ws + 80 * MB);
    bf16_t* Vt   = (bf16_t*)(ws + 96 * MB);
    bf16_t* Ob   = (bf16_t*)(ws + 112 * MB);
    bf16_t* WQKh = (bf16_t*)(ws + 128 * MB); // [2048][1024] = 4 MB; dead after proj -> ML
    bf16_t* WQKl = (bf16_t*)(ws + 132 * MB);
    bf16_t* Wvh  = (bf16_t*)(ws + 136 * MB);
    bf16_t* Woh  = (bf16_t*)(ws + 138 * MB);
    bf16_t* Opart = (bf16_t*)(ws);           // [2][8192][1024] bf16 = 32 MB
    float*  ML    = (float*)(ws + 128 * MB); // [2][8192][16][2] f32 = 2 MB

    // conversions / splits.  x: 2,097,152 float4; each W: 262,144 float4.
    cvt_split_k<<<8192, 256, 0, stream>>>(x, xh, xl, 2097152);
    cvt_weights_k<<<dim3(1024, 4), 256, 0, stream>>>(Wq, Wk, Wv, Wo,
                                                     WQKh, WQKl, Wvh, Woh);

    // projections: fused Q+K (N=2048), then V
    gemm_splitQK<<<dim3(16, 64), 256, 0, stream>>>(xh, xl, WQKh, WQKl,
                                                   Qh, Ql, Kh, Kl, 1024);
    gemm_bt<1><<<dim3(8, 64), 256, 0, stream>>>(xh, Wvh, Vt, 8192, 1024, 1024);

    // attention: paired q-tiles, XCD-local (h,b,hf) groups, 1024 identical blocks
    attn_k<<<dim3(8, 16, 8), 256, 0, stream>>>(Qh, Ql, Kh, Kl, Vt, Opart, ML);
    attn_combine_k<<<4096, 256, 0, stream>>>(Opart, Opart + (size_t)8 * 1024 * 1024, ML, Ob);

    // output projection (fp32 epilogue to d_out)
    gemm_bt<2><<<dim3(8, 64), 256, 0, stream>>>(Ob, Woh, d_out, 8192, 1024, 1024);
}

// Round 21
// 286.972 us; speedup vs baseline: 1.1412x; 1.0058x over previous
//
#include <hip/hip_runtime.h>
#include <hip/hip_bf16.h>

typedef __bf16 bf16_t;
typedef __bf16 bf16x4 __attribute__((ext_vector_type(4)));
typedef __bf16 bf16x8 __attribute__((ext_vector_type(8)));
typedef float f32x4 __attribute__((ext_vector_type(4)));

#define MFMA16(a, b, c) __builtin_amdgcn_mfma_f32_16x16x32_bf16((a), (b), (c), 0, 0, 0)

#if __has_builtin(__builtin_amdgcn_exp2f)
#define EXP2(x) __builtin_amdgcn_exp2f(x)
#else
#define EXP2(x) exp2f(x)
#endif

__device__ inline void g2l16(const void* g, void* l) {
    __builtin_amdgcn_global_load_lds((const __attribute__((address_space(1))) void*)g,
                                     (__attribute__((address_space(3))) void*)l, 16, 0, 0);
}

// ---------------- fused conversions: x split + all four weights, one launch ----------------
// blockIdx.y == 0..31: x (hi,lo) split, 65536 float4 per y-slice (2,097,152 total).
// blockIdx.y == 32: Wq * 0.125*log2e split -> rows [0,1024) of (WQKh, WQKl)  [4 x-slices wide]
// blockIdx.y == 36: Wk split -> rows [1024,2048);  y == 40: Wv;  y == 44: Wo.
__global__ __launch_bounds__(256) void cvt_all_k(const float* __restrict__ x,
                                                 const float* __restrict__ Wq,
                                                 const float* __restrict__ Wk,
                                                 const float* __restrict__ Wv,
                                                 const float* __restrict__ Wo,
                                                 bf16_t* __restrict__ xh, bf16_t* __restrict__ xl,
                                                 bf16_t* __restrict__ WQKh, bf16_t* __restrict__ WQKl,
                                                 bf16_t* __restrict__ Wvh, bf16_t* __restrict__ Woh) {
    const int y = blockIdx.y;
    if (y < 32) {
        const int i = (y * 256 + (int)blockIdx.x) * 256 + threadIdx.x;   // 2,097,152 float4
        float4 v = reinterpret_cast<const float4*>(x)[i];
        bf16x4 h, l;
        float f;
        f = v.x; h[0] = (__bf16)f; l[0] = (__bf16)(f - (float)h[0]);
        f = v.y; h[1] = (__bf16)f; l[1] = (__bf16)(f - (float)h[1]);
        f = v.z; h[2] = (__bf16)f; l[2] = (__bf16)(f - (float)h[2]);
        f = v.w; h[3] = (__bf16)f; l[3] = (__bf16)(f - (float)h[3]);
        reinterpret_cast<bf16x4*>(xh)[i] = h;
        reinterpret_cast<bf16x4*>(xl)[i] = l;
        return;
    }
    const int which = (y - 32) >> 2;                 // 0:Wq 1:Wk 2:Wv 3:Wo
    const int ys = (y - 32) & 3;
    const int i = (ys * 256 + (int)blockIdx.x) * 256 + threadIdx.x;   // 262,144 float4
    if (which <= 1) {
        const float c = (which == 0) ? 0.125f * 1.4426950408889634f : 1.0f;
        const int off = which * 262144;
        float4 v = reinterpret_cast<const float4*>(which == 0 ? Wq : Wk)[i];
        bf16x4 h, l;
        float f;
        f = v.x * c; h[0] = (__bf16)f; l[0] = (__bf16)(f - (float)h[0]);
        f = v.y * c; h[1] = (__bf16)f; l[1] = (__bf16)(f - (float)h[1]);
        f = v.z * c; h[2] = (__bf16)f; l[2] = (__bf16)(f - (float)h[2]);
        f = v.w * c; h[3] = (__bf16)f; l[3] = (__bf16)(f - (float)h[3]);
        reinterpret_cast<bf16x4*>(WQKh)[i + off] = h;
        reinterpret_cast<bf16x4*>(WQKl)[i + off] = l;
    } else {
        float4 v = reinterpret_cast<const float4*>(which == 2 ? Wv : Wo)[i];
        bf16x4 o;
        o[0] = (__bf16)v.x; o[1] = (__bf16)v.y; o[2] = (__bf16)v.z; o[3] = (__bf16)v.w;
        reinterpret_cast<bf16x4*>(which == 2 ? Wvh : Woh)[i] = o;
    }
}

// XCD-aware tile swizzle; LGX = log2(gridDim.x); nwg % 8 == 0.
template <int LGX>
__device__ inline void xcd_tile(int& bm, int& bn) {
    const int id = blockIdx.y * (1 << LGX) + blockIdx.x;
    const int cpx = ((1 << LGX) * gridDim.y) >> 3;
    const int swz = (id & 7) * cpx + (id >> 3);
    bn = swz & ((1 << LGX) - 1);
    bm = swz >> LGX;
}

// ---------------- GEMM: C[m,n] = sum_k A[m,k] * B[n,k] (plain bf16) ----------------
// MODE 0: bf16 row-major; MODE 1: bf16 transposed per batch (Vt) via LDS
// transpose + coalesced stores; MODE 2: fp32 row-major.
template <int MODE>
__global__ __launch_bounds__(256) void gemm_bt(const bf16_t* __restrict__ A,
                                               const bf16_t* __restrict__ B,
                                               void* __restrict__ Cout,
                                               int M, int N, int K) {
    __shared__ __align__(16) bf16_t As[128 * 32];
    __shared__ __align__(16) bf16_t Bs[128 * 32];
    const int tid = threadIdx.x;
    const int w = tid >> 6, lane = tid & 63;
    const int l15 = lane & 15, g = lane >> 4;
    const int wr = w >> 1, wc = w & 1;
    int bm, bn;
    xcd_tile<3>(bm, bn);

    const f32x4 fz = {0.f, 0.f, 0.f, 0.f};
    f32x4 acc[4][4];
#pragma unroll
    for (int m = 0; m < 4; m++)
#pragma unroll
        for (int n = 0; n < 4; n++) acc[m][n] = fz;

    const bf16_t* Ab = A + (size_t)bm * 128 * K;
    const bf16_t* Bb = B + (size_t)bn * 128 * K;
    const int rowL = w * 16 + (lane >> 2);
    const int c8 = (lane & 3) * 8;
    char* AsD = (char*)As + w * 1024;
    char* BsD = (char*)Bs + w * 1024;

    for (int k0 = 0; k0 < K; k0 += 32) {
        g2l16(Ab + (size_t)rowL * K + k0 + c8, AsD);
        g2l16(Ab + (size_t)(rowL + 64) * K + k0 + c8, AsD + 4096);
        g2l16(Bb + (size_t)rowL * K + k0 + c8, BsD);
        g2l16(Bb + (size_t)(rowL + 64) * K + k0 + c8, BsD + 4096);
        __syncthreads();

        bf16x8 af[4], bfr[4];
        const bf16x8* Ap = reinterpret_cast<const bf16x8*>(As + (wr * 64 + l15) * 32 + g * 8);
#pragma unroll
        for (int m = 0; m < 4; m++) af[m] = Ap[m * 64];
        const bf16x8* Bp = reinterpret_cast<const bf16x8*>(Bs + (wc * 64 + l15) * 32 + g * 8);
#pragma unroll
        for (int n = 0; n < 4; n++) bfr[n] = Bp[n * 64];
#pragma unroll
        for (int m = 0; m < 4; m++)
#pragma unroll
            for (int n = 0; n < 4; n++) acc[m][n] = MFMA16(af[m], bfr[n], acc[m][n]);
        __syncthreads();
    }

    if constexpr (MODE == 1) {
        // transpose C through LDS, then coalesced Vt[b][v][s] stores
        __shared__ __align__(16) bf16_t Ct[128][130];
        const int colL = wc * 64 + l15;     // + n*16 (v within tile)
        const int rowB = wr * 64 + g * 4;   // + m*16 (s within tile)
#pragma unroll
        for (int m = 0; m < 4; m++)
#pragma unroll
            for (int n = 0; n < 4; n++) {
                bf16x4 c4;
#pragma unroll
                for (int r = 0; r < 4; r++) c4[r] = (__bf16)acc[m][n][r];
                *reinterpret_cast<bf16x4*>(&Ct[colL + n * 16][rowB + m * 16]) = c4;
            }
        __syncthreads();
        const int bb = (bm * 128) >> 11;
        const int s0 = (bm * 128) & 2047;
        const int vg = tid >> 3, scc = tid & 7;
        bf16_t* Vtb = (bf16_t*)Cout + (size_t)bb * 1024 * 2048;
#pragma unroll
        for (int u = 0; u < 4; u++)
#pragma unroll
            for (int hh = 0; hh < 2; hh++) {
                const int v = u * 32 + vg;
                const int s = hh * 64 + scc * 8;
                *reinterpret_cast<int4*>(&Vtb[(size_t)(bn * 128 + v) * 2048 + s0 + s]) =
                    *reinterpret_cast<const int4*>(&Ct[v][s]);
            }
    } else {
        const int row0 = bm * 128 + wr * 64 + g * 4;
        const int col0 = bn * 128 + wc * 64 + l15;
#pragma unroll
        for (int m = 0; m < 4; m++)
#pragma unroll
            for (int n = 0; n < 4; n++)
#pragma unroll
                for (int r = 0; r < 4; r++) {
                    int row = row0 + m * 16 + r;
                    int col = col0 + n * 16;
                    float v = acc[m][n][r];
                    if (MODE == 0) {
                        ((bf16_t*)Cout)[(size_t)row * N + col] = (__bf16)v;
                    } else {
                        ((float*)Cout)[(size_t)row * N + col] = v;
                    }
                }
    }
}

// ---------------- fused Q+K split-pair GEMM ----------------
// B = concat(Wq', Wk') rows 0..2047; bn<8 -> (Qh,Ql), bn>=8 -> (Kh,Kl).
__global__ __launch_bounds__(256) void gemm_splitQK(const bf16_t* __restrict__ Ah,
                                                    const bf16_t* __restrict__ Al,
                                                    const bf16_t* __restrict__ Bh,
                                                    const bf16_t* __restrict__ Bl,
                                                    bf16_t* __restrict__ Qh,
                                                    bf16_t* __restrict__ Ql,
                                                    bf16_t* __restrict__ Kh,
                                                    bf16_t* __restrict__ Kl,
                                                    int K) {
    __shared__ __align__(16) bf16_t Ash[128 * 32];
    __shared__ __align__(16) bf16_t Asl[128 * 32];
    __shared__ __align__(16) bf16_t Bsh[128 * 32];
    __shared__ __align__(16) bf16_t Bsl[128 * 32];
    const int tid = threadIdx.x;
    const int w = tid >> 6, lane = tid & 63;
    const int l15 = lane & 15, g = lane >> 4;
    const int wr = w >> 1, wc = w & 1;
    int bm, bn;
    xcd_tile<4>(bm, bn);    // grid 16 x 64

    const f32x4 fz = {0.f, 0.f, 0.f, 0.f};
    f32x4 acc[4][4];
#pragma unroll
    for (int m = 0; m < 4; m++)
#pragma unroll
        for (int n = 0; n < 4; n++) acc[m][n] = fz;

    const size_t aoff = (size_t)bm * 128 * K;
    const size_t boff = (size_t)bn * 128 * K;
    const int rowL = w * 16 + (lane >> 2);
    const int c8 = (lane & 3) * 8;
    const size_t g0 = (size_t)rowL * K + c8;
    const size_t g1 = (size_t)(rowL + 64) * K + c8;

    for (int k0 = 0; k0 < K; k0 += 32) {
        g2l16(Ah + aoff + g0 + k0, (char*)Ash + w * 1024);
        g2l16(Ah + aoff + g1 + k0, (char*)Ash + w * 1024 + 4096);
        g2l16(Al + aoff + g0 + k0, (char*)Asl + w * 1024);
        g2l16(Al + aoff + g1 + k0, (char*)Asl + w * 1024 + 4096);
        g2l16(Bh + boff + g0 + k0, (char*)Bsh + w * 1024);
        g2l16(Bh + boff + g1 + k0, (char*)Bsh + w * 1024 + 4096);
        g2l16(Bl + boff + g0 + k0, (char*)Bsl + w * 1024);
        g2l16(Bl + boff + g1 + k0, (char*)Bsl + w * 1024 + 4096);
        __syncthreads();

        bf16x8 ah[4], al[4], bh[4], bl[4];
        const int ao = (wr * 64 + l15) * 32 + g * 8;
        const int bo = (wc * 64 + l15) * 32 + g * 8;
#pragma unroll
        for (int m = 0; m < 4; m++) {
            ah[m] = *reinterpret_cast<const bf16x8*>(Ash + ao + m * 512);
            al[m] = *reinterpret_cast<const bf16x8*>(Asl + ao + m * 512);
        }
#pragma unroll
        for (int n = 0; n < 4; n++) {
            bh[n] = *reinterpret_cast<const bf16x8*>(Bsh + bo + n * 512);
            bl[n] = *reinterpret_cast<const bf16x8*>(Bsl + bo + n * 512);
        }
#pragma unroll
        for (int m = 0; m < 4; m++)
#pragma unroll
            for (int n = 0; n < 4; n++) {
                acc[m][n] = MFMA16(ah[m], bh[n], acc[m][n]);
                acc[m][n] = MFMA16(al[m], bh[n], acc[m][n]);
                acc[m][n] = MFMA16(ah[m], bl[n], acc[m][n]);
            }
        __syncthreads();
    }

    bf16_t* Ch = (bn < 8) ? Qh : Kh;
    bf16_t* Cl = (bn < 8) ? Ql : Kl;
    const int row0 = bm * 128 + wr * 64 + g * 4;
    const int col0 = (bn * 128 + wc * 64 + l15) & 1023;
#pragma unroll
    for (int m = 0; m < 4; m++)
#pragma unroll
        for (int n = 0; n < 4; n++)
#pragma unroll
            for (int r = 0; r < 4; r++) {
                size_t idx = (size_t)(row0 + m * 16 + r) * 1024 + col0 + n * 16;
                float v = acc[m][n][r];
                bf16_t h = (__bf16)v;
                Ch[idx] = h;
                Cl[idx] = (__bf16)(v - (float)h);
            }
}

// ---------------- causal flash attention: PAIRED q-tiles + XCD-local groups ----------------
// Converged configuration (~128 us): 16x16 MFMA, VGPR 120 = 4 waves/SIMD.
// Structural constraints (measured): >128 VGPR halves occupancy (R16/R19);
// 32x32 MFMA adds VGPR + 4.5x bank conflicts (R19); barrier/phase/KV-split
// rearrangements null (R7/R10/R11); direct-L2 K/V gather 2.8x worse (R14).
__global__ __launch_bounds__(256) void attn_k(const bf16_t* __restrict__ Qh,
                                              const bf16_t* __restrict__ Ql,
                                              const bf16_t* __restrict__ Kh,
                                              const bf16_t* __restrict__ Kl,
                                              const bf16_t* __restrict__ Vt,
                                              bf16_t* __restrict__ Opart,
                                              float* __restrict__ ML) {
    const int L = (int)blockIdx.x + 8 * ((int)blockIdx.y + 16 * (int)blockIdx.z);
    const int px = (L >> 3) & 7;               // pair index 0..7
    const int G = (L & 7) | ((L >> 6) << 3);   // group 0..127
    const int h = G & 15;
    const int zz = G >> 4;
    const int b = zz >> 1, hf = zz & 1;
    const int tid = threadIdx.x, w = tid >> 6, lane = tid & 63;
    const int l15 = lane & 15, g = lane >> 4;

    __shared__ __align__(16) bf16_t Ks[4096];      // K hi [kv=64][d=64] swizzled
    __shared__ __align__(16) bf16_t Ls[4096];      // K lo
    __shared__ __align__(16) bf16_t Vs[4096];      // V^T  [v=64][kv=64] swizzled
    __shared__ __align__(16) bf16_t Ps[4][1024];   // per-wave P [q=16][kv=64]

    const size_t boff = (size_t)b * 2048 * 1024;
    const size_t vbase = (size_t)b * 1024 * 2048 + (size_t)(h * 64) * 2048;

    // staging: thread -> (row sr, 16B-chunk sc); rows sr and sr+32 per array.
    const int sr = tid >> 3;       // 0..31
    const int sc = tid & 7;        // 0..7
    const int wo0 = sr * 8 + (sc ^ (sr & 7));           // int4 index, swizzled
    const int wo1 = wo0 + 256;                          // (sr+32)&7 == sr&7

    int4 sK0, sK1, sL0, sL1, sV0, sV1;
#define STAGE_LOAD(T)                                                               \
    do {                                                                            \
        const int kv0_ = (T) * 64;                                                  \
        const bf16_t* kp = Kh + boff + (size_t)(kv0_ + sr) * 1024 + h * 64 + sc * 8;\
        const bf16_t* lp = Kl + boff + (size_t)(kv0_ + sr) * 1024 + h * 64 + sc * 8;\
        const bf16_t* vp = Vt + vbase + (size_t)sr * 2048 + kv0_ + sc * 8;          \
        sK0 = *(const int4*)kp; sK1 = *(const int4*)(kp + 32 * 1024);               \
        sL0 = *(const int4*)lp; sL1 = *(const int4*)(lp + 32 * 1024);               \
        sV0 = *(const int4*)vp; sV1 = *(const int4*)(vp + 32 * 2048);               \
    } while (0)
#define STAGE_WRITE()                                                               \
    do {                                                                            \
        ((int4*)Ks)[wo0] = sK0; ((int4*)Ks)[wo1] = sK1;                             \
        ((int4*)Ls)[wo0] = sL0; ((int4*)Ls)[wo1] = sL1;                             \
        ((int4*)Vs)[wo0] = sV0; ((int4*)Vs)[wo1] = sV1;                             \
    } while (0)

    const f32x4 fz = {0.f, 0.f, 0.f, 0.f};
    bf16_t* Op = Opart + (size_t)hf * 8 * 1024 * 1024;
    float* MLp = ML + (size_t)hf * 8192 * 16 * 2;

#pragma unroll 1
    for (int it = 0; it < 2; ++it) {
        const int qt = it ? (15 - px) : px;
        const int qrw = qt * 128 + w * 32;             // wave's first q row

        // Q fragments (hi/lo) — B-operand layout: lane (j=l15, g) = Q[row][g*8..+8]
        bf16x8 qhf[2][2], qlf[2][2];
#pragma unroll
        for (int m = 0; m < 2; m++)
#pragma unroll
            for (int kk = 0; kk < 2; kk++) {
                size_t qi = boff + (size_t)(qrw + m * 16 + l15) * 1024 + h * 64 + kk * 32 + g * 8;
                qhf[m][kk] = *reinterpret_cast<const bf16x8*>(Qh + qi);
                qlf[m][kk] = *reinterpret_cast<const bf16x8*>(Ql + qi);
            }

        f32x4 oacc[2][4];              // O^T frag: v = n*16+g*4+r, q = l15
#pragma unroll
        for (int m = 0; m < 2; m++)
#pragma unroll
            for (int n = 0; n < 4; n++) oacc[m][n] = fz;
        float mst[2] = {-__builtin_inff(), -__builtin_inff()};
        float lst[2] = {0.f, 0.f};

        const int t0 = hf ? qt + 1 : 0;
        const int t1 = hf ? 2 * qt + 1 : qt;   // inclusive
        STAGE_LOAD(t0);
        STAGE_WRITE();                 // compiler inserts vmcnt waits before reg use
        __syncthreads();

        for (int t = t0; t <= t1; ++t) {
            const int kv0 = t * 64;
            if (t < t1) STAGE_LOAD(t + 1);   // flies under this tile's compute

            if (kv0 <= qrw + 31) {   // wave-uniform: skip fully-masked tiles
                // ---- QK^T swapped (S^T; split precision: 3 MFMAs) ----
                f32x4 st[2][4];
#pragma unroll
                for (int m = 0; m < 2; m++)
#pragma unroll
                    for (int n = 0; n < 4; n++) st[m][n] = fz;
                __builtin_amdgcn_s_setprio(1);
#pragma unroll
                for (int kk = 0; kk < 2; kk++)
#pragma unroll
                    for (int n = 0; n < 4; n++) {
                        const int off = (n * 16 + l15) * 64 + (((kk * 4 + g) ^ (l15 & 7)) << 3);
                        bf16x8 khf = *reinterpret_cast<const bf16x8*>(&Ks[off]);
                        bf16x8 klf = *reinterpret_cast<const bf16x8*>(&Ls[off]);
#pragma unroll
                        for (int m = 0; m < 2; m++) {
                            st[m][n] = MFMA16(khf, qhf[m][kk], st[m][n]);   // Kh·Qh
                            st[m][n] = MFMA16(khf, qlf[m][kk], st[m][n]);   // Kh·Ql
                            st[m][n] = MFMA16(klf, qhf[m][kk], st[m][n]);   // Kl·Qh
                        }
                    }
                __builtin_amdgcn_s_setprio(0);

                // ---- per-m: in-lane softmax (base-2) -> packed P -> PV ----
                const bool diag = (kv0 + 63 > qrw);
#pragma unroll
                for (int m = 0; m < 2; m++) {
                    const int qrow = qrw + m * 16 + l15;   // this lane's q row
                    float pmax = -__builtin_inff();
                    if (diag) {
                        const int klim = qrow - kv0;       // mask if n*16+g*4+r > klim
#pragma unroll
                        for (int n = 0; n < 4; n++)
#pragma unroll
                            for (int r = 0; r < 4; r++) {
                                float s = st[m][n][r];
                                if (n * 16 + g * 4 + r > klim) s = -__builtin_inff();
                                st[m][n][r] = s;
                                pmax = fmaxf(pmax, s);
                            }
                    } else {
#pragma unroll
                        for (int n = 0; n < 4; n++)
#pragma unroll
                            for (int r = 0; r < 4; r++) pmax = fmaxf(pmax, st[m][n][r]);
                    }
                    pmax = fmaxf(pmax, __shfl_xor(pmax, 16));
                    pmax = fmaxf(pmax, __shfl_xor(pmax, 32));
                    const float mn = fmaxf(mst[m], pmax);
                    const float alpha = EXP2(mst[m] - mn);
                    mst[m] = mn;
                    float rs = 0.f;
#pragma unroll
                    for (int n = 0; n < 4; n++)
#pragma unroll
                        for (int r = 0; r < 4; r++) {
                            float pe = EXP2(st[m][n][r] - mn);
                            st[m][n][r] = pe;
                            rs += pe;
                        }
                    rs += __shfl_xor(rs, 16);
                    rs += __shfl_xor(rs, 32);
                    lst[m] = lst[m] * alpha + rs;
#pragma unroll
                    for (int n = 0; n < 4; n++) oacc[m][n] *= alpha;

                    // P -> per-wave LDS, packed 8B: row=l15 (q), col=n*16+g*4
#pragma unroll
                    for (int n = 0; n < 4; n++) {
                        bf16x4 p4;
#pragma unroll
                        for (int r = 0; r < 4; r++) p4[r] = (__bf16)st[m][n][r];
                        const int chunk = (2 * n + (g >> 1)) ^ (l15 & 7);
                        *reinterpret_cast<bf16x4*>(&Ps[w][l15 * 64 + chunk * 8 + (g & 1) * 4]) = p4;
                    }

                    asm volatile("s_waitcnt lgkmcnt(0)" ::: "memory");
                    __builtin_amdgcn_sched_barrier(0);

                    // PV: O^T += V^T · P  (A = V^T frag, B = P frag)
                    __builtin_amdgcn_s_setprio(1);
#pragma unroll
                    for (int kk = 0; kk < 2; kk++) {
                        bf16x8 pa = *reinterpret_cast<const bf16x8*>(
                            &Ps[w][l15 * 64 + (((kk * 4 + g) ^ (l15 & 7)) << 3)]);
#pragma unroll
                        for (int n = 0; n < 4; n++) {
                            const int voff = (n * 16 + l15) * 64 + (((kk * 4 + g) ^ (l15 & 7)) << 3);
                            bf16x8 vf = *reinterpret_cast<const bf16x8*>(&Vs[voff]);
                            oacc[m][n] = MFMA16(vf, pa, oacc[m][n]);
                        }
                    }
                    __builtin_amdgcn_s_setprio(0);
                }
            }
            __syncthreads();                 // all waves done reading Ks/Ls/Vs
            if (t < t1) STAGE_WRITE();       // loads arrived long ago; write swizzled
            __syncthreads();                 // writes visible for next tile
        }

        // ---- epilogue: unnormalized partial (packed 8B) + (m,l) by g==0 lanes ----
#pragma unroll
        for (int m = 0; m < 2; m++) {
            const int qrow = qrw + m * 16 + l15;
#pragma unroll
            for (int n = 0; n < 4; n++) {
                bf16x4 o4;
#pragma unroll
                for (int r = 0; r < 4; r++) o4[r] = (__bf16)oacc[m][n][r];
                *reinterpret_cast<bf16x4*>(&Op[boff + (size_t)qrow * 1024 + h * 64 + n * 16 + g * 4]) = o4;
            }
            if (g == 0) {
                const int grow = b * 2048 + qrow;
                MLp[(grow * 16 + h) * 2 + 0] = mst[m];
                MLp[(grow * 16 + h) * 2 + 1] = lst[m];
            }
        }
        // loop's final __syncthreads already passed; LDS safe to restage next item
    }
#undef STAGE_LOAD
#undef STAGE_WRITE
}

// ---------------- split-KV combine: O = (w1*O1 + w2*O2) ----------------
__global__ __launch_bounds__(256) void attn_combine_k(const bf16_t* __restrict__ Op0,
                                                      const bf16_t* __restrict__ Op1,
                                                      const float* __restrict__ ML,
                                                      bf16_t* __restrict__ O) {
    const int t = blockIdx.x * 256 + threadIdx.x;   // 8-elem groups, 1,048,576 total
    const int row = t >> 7;
    const int h = (t >> 3) & 15;
    const float m1 = ML[(row * 16 + h) * 2 + 0];
    const float l1 = ML[(row * 16 + h) * 2 + 1];
    const float m2 = ML[(8192 * 16 + row * 16 + h) * 2 + 0];
    const float l2 = ML[(8192 * 16 + row * 16 + h) * 2 + 1];
    const float mx = fmaxf(m1, m2);
    float w1 = (l1 > 0.f) ? EXP2(m1 - mx) : 0.f;
    float w2 = (l2 > 0.f) ? EXP2(m2 - mx) : 0.f;
    const float inv = 1.f / (l1 * w1 + l2 * w2);
    w1 *= inv; w2 *= inv;
    bf16x8 a = reinterpret_cast<const bf16x8*>(Op0)[t];
    bf16x8 c = reinterpret_cast<const bf16x8*>(Op1)[t];
    bf16x8 o;
#pragma unroll
    for (int i = 0; i < 8; i++) o[i] = (__bf16)((float)a[i] * w1 + (float)c[i] * w2);
    reinterpret_cast<bf16x8*>(O)[t] = o;
}

extern "C" void kernel_launch(void* const* d_in, const int* in_sizes, int n_in,
                              void* d_out, int out_size, void* d_ws, size_t ws_size,
                              hipStream_t stream) {
    const float* x  = (const float*)d_in[0];
    const float* Wq = (const float*)d_in[1];
    const float* Wk = (const float*)d_in[2];
    const float* Wv = (const float*)d_in[3];
    const float* Wo = (const float*)d_in[4];

    char* ws = (char*)d_ws;
    const size_t MB = (size_t)1 << 20;
    bf16_t* xh   = (bf16_t*)(ws);            // dead after projections -> Opart
    bf16_t* xl   = (bf16_t*)(ws + 16 * MB);
    bf16_t* Qh   = (bf16_t*)(ws + 32 * MB);
    bf16_t* Ql   = (bf16_t*)(ws + 48 * MB);
    bf16_t* Kh   = (bf16_t*)(ws + 64 * MB);
    bf16_t* Kl   = (bf16_t*)(ws + 80 * MB);
    bf16_t* Vt   = (bf16_t*)(ws + 96 * MB);
    bf16_t* Ob   = (bf16_t*)(ws + 112 * MB);
    bf16_t* WQKh = (bf16_t*)(ws + 128 * MB); // [2048][1024] = 4 MB; dead after proj -> ML
    bf16_t* WQKl = (bf16_t*)(ws + 132 * MB);
    bf16_t* Wvh  = (bf16_t*)(ws + 136 * MB);
    bf16_t* Woh  = (bf16_t*)(ws + 138 * MB);
    bf16_t* Opart = (bf16_t*)(ws);           // [2][8192][1024] bf16 = 32 MB
    float*  ML    = (float*)(ws + 128 * MB); // [2][8192][16][2] f32 = 2 MB

    // all conversions in one launch: y<32 = x split (32x256 blocks),
    // y=32..47 = the four weights (4 slices each).
    cvt_all_k<<<dim3(256, 48), 256, 0, stream>>>(x, Wq, Wk, Wv, Wo,
                                                 xh, xl, WQKh, WQKl, Wvh, Woh);

    // projections: fused Q+K (N=2048), then V
    gemm_splitQK<<<dim3(16, 64), 256, 0, stream>>>(xh, xl, WQKh, WQKl,
                                                   Qh, Ql, Kh, Kl, 1024);
    gemm_bt<1><<<dim3(8, 64), 256, 0, stream>>>(xh, Wvh, Vt, 8192, 1024, 1024);

    // attention: paired q-tiles, XCD-local (h,b,hf) groups, 1024 identical blocks
    attn_k<<<dim3(8, 16, 8), 256, 0, stream>>>(Qh, Ql, Kh, Kl, Vt, Opart, ML);
    attn_combine_k<<<4096, 256, 0, stream>>>(Opart, Opart + (size_t)8 * 1024 * 1024, ML, Ob);

    // output projection (fp32 epilogue to d_out)
    gemm_bt<2><<<dim3(8, 64), 256, 0, stream>>>(Ob, Woh, d_out, 8192, 1024, 1024);
}